// Round 1
// baseline (209.696 us; speedup 1.0000x reference)
//
#include <hip/hip_runtime.h>

#define ALPHA 0.90483741803595957f

// ---------------------------------------------------------------------------
// K0: fold avgpool into conv kernels.
// W1eff[oc][ch][u][v] (4x2x8x8): conv1 5x5 pad2 + pool4  => 8x8 stride-4 conv
// W2eff[oc][ch][u][v] (8x4x4x4): conv2 3x3 pad1 + pool2  => 4x4 stride-2 conv
// ---------------------------------------------------------------------------
__global__ void prep_weights(const float* __restrict__ w1, const float* __restrict__ w2,
                             float* __restrict__ w1e, float* __restrict__ w2e) {
    int idx = blockIdx.x * 256 + threadIdx.x;
    if (idx < 512) {
        int v = idx & 7, u = (idx >> 3) & 7, ch = (idx >> 6) & 1, oc = idx >> 7;
        float s = 0.f;
        for (int a = 0; a < 5; ++a) {
            int i = u - a; if (i < 0 || i > 3) continue;
            for (int b = 0; b < 5; ++b) {
                int j = v - b; if (j < 0 || j > 3) continue;
                s += w1[((oc * 2 + ch) * 5 + a) * 5 + b];
            }
        }
        w1e[idx] = s * (1.f / 16.f);
    } else if (idx < 1024) {
        int k = idx - 512;
        int v = k & 3, u = (k >> 2) & 3, ch = (k >> 4) & 3, oc = k >> 6;
        float s = 0.f;
        for (int a = 0; a < 3; ++a) {
            int i = u - a; if (i < 0 || i > 1) continue;
            for (int b = 0; b < 3; ++b) {
                int j = v - b; if (j < 0 || j > 1) continue;
                s += w2[((oc * 4 + ch) * 3 + a) * 3 + b];
            }
        }
        w2e[k] = s * 0.25f;
    }
}

// ---------------------------------------------------------------------------
// K1: conv1 + pool4 via 8x8/stride-4 effective kernel.
// 4 images per block (1 wave per image). Padded LDS tile 2ch x 36x36 per image.
// Each lane computes one (p,q) for all 4 output channels (4 accs, 128 MACs ea).
// ---------------------------------------------------------------------------
__global__ __launch_bounds__(256) void conv1_pool(const float* __restrict__ x,
                                                  const float* __restrict__ w1e,
                                                  float* __restrict__ y1) {
    __shared__ __align__(16) float tile[4][2][36][36];  // 41472 B
    int tid = threadIdx.x;

    // zero the whole tile (covers the pad borders)
    float4* t4 = (float4*)&tile[0][0][0][0];
    #pragma unroll
    for (int k = 0; k < 11; ++k) {
        int i = tid + k * 256;
        if (i < 2592) t4[i] = make_float4(0.f, 0.f, 0.f, 0.f);
    }
    __syncthreads();

    int li = tid >> 6, pos = tid & 63;
    long gi = (long)blockIdx.x * 4 + li;            // bt index, < 12800
    const float* src = x + gi * 2048;               // 2ch*32*32
    #pragma unroll
    for (int k = 0; k < 8; ++k) {
        int e = k * 256 + pos * 4;                  // 16B-aligned
        float4 d = *(const float4*)(src + e);
        int ch = e >> 10, rem = e & 1023, r = rem >> 5, c = rem & 31;
        float* dst = &tile[li][ch][r + 2][c + 2];
        dst[0] = d.x; dst[1] = d.y; dst[2] = d.z; dst[3] = d.w;
    }
    __syncthreads();

    int p = pos >> 3, q = pos & 7;
    float acc0 = 0.f, acc1 = 0.f, acc2 = 0.f, acc3 = 0.f;
    #pragma unroll
    for (int ch = 0; ch < 2; ++ch) {
        #pragma unroll
        for (int r = 0; r < 8; ++r) {
            const float* row = &tile[li][ch][4 * p + r][4 * q];  // 16B aligned
            float4 a = *(const float4*)row;
            float4 b = *(const float4*)(row + 4);
            float in[8] = {a.x, a.y, a.z, a.w, b.x, b.y, b.z, b.w};
            #pragma unroll
            for (int c = 0; c < 8; ++c) {
                float xi = in[c];
                acc0 += w1e[((0 * 2 + ch) * 8 + r) * 8 + c] * xi;  // uniform -> s_load
                acc1 += w1e[((1 * 2 + ch) * 8 + r) * 8 + c] * xi;
                acc2 += w1e[((2 * 2 + ch) * 8 + r) * 8 + c] * xi;
                acc3 += w1e[((3 * 2 + ch) * 8 + r) * 8 + c] * xi;
            }
        }
    }
    float* dst = y1 + gi * 256 + pos;   // [bt][oc][p][q]
    dst[0] = acc0; dst[64] = acc1; dst[128] = acc2; dst[192] = acc3;
}

// ---------------------------------------------------------------------------
// K2: exp_leak + LIF scan over T for stage 1. One thread per (b, f), f<256.
// ---------------------------------------------------------------------------
__global__ void scan1(const float* __restrict__ y1, float* __restrict__ spk) {
    int idx = blockIdx.x * 256 + threadIdx.x;   // 32768 = 128 b * 256 f
    int b = idx >> 8, f = idx & 255;
    const float* p = y1 + (long)b * 100 * 256 + f;
    float* o = spk + (long)b * 100 * 256 + f;
    float v1 = 0.f, v2 = 0.f;
    float xt = p[0];
    #pragma unroll 5
    for (int t = 0; t < 100; ++t) {
        float xn = (t < 99) ? p[(t + 1) * 256] : 0.f;  // prefetch
        v1 = ALPHA * v1 + xt;
        v2 = ALPHA * v2 + v1;
        float s = (v2 >= 1.f) ? 1.f : 0.f;
        o[t * 256] = s;
        v2 -= s;
        xt = xn;
    }
}

// ---------------------------------------------------------------------------
// K3: conv2 + pool2 via 4x4/stride-2 effective kernel.
// 2 images per block. Padded LDS tile 4ch x 10x10 per image.
// ---------------------------------------------------------------------------
__global__ __launch_bounds__(256) void conv2_pool(const float* __restrict__ spk,
                                                  const float* __restrict__ w2e,
                                                  float* __restrict__ y2) {
    __shared__ __align__(16) float tile[2][4][10][10];  // 800 floats
    int tid = threadIdx.x;
    float4* t4 = (float4*)&tile[0][0][0][0];
    if (tid < 200) t4[tid] = make_float4(0.f, 0.f, 0.f, 0.f);
    __syncthreads();

    const float* src = spk + (long)blockIdx.x * 512;
    #pragma unroll
    for (int k = 0; k < 2; ++k) {
        int e = k * 256 + tid;
        float d = src[e];
        int li = e >> 8, f = e & 255, ch = f >> 6, rem = f & 63, r = rem >> 3, c = rem & 7;
        tile[li][ch][r + 1][c + 1] = d;
    }
    __syncthreads();

    int li = tid >> 7, tpos = tid & 127;
    int oc = tpos >> 4, p = (tpos >> 2) & 3, q = tpos & 3;
    float acc = 0.f;
    #pragma unroll
    for (int ch = 0; ch < 4; ++ch) {
        #pragma unroll
        for (int r = 0; r < 4; ++r) {
            const float* row = &tile[li][ch][2 * p + r][2 * q];
            #pragma unroll
            for (int c = 0; c < 4; ++c)
                acc += w2e[((oc * 4 + ch) * 4 + r) * 4 + c] * row[c];
        }
    }
    long gi = (long)blockIdx.x * 2 + li;
    y2[gi * 128 + tpos] = acc;   // [bt][oc][p][q]
}

// ---------------------------------------------------------------------------
// K4: exp_leak + LIF scan for stage 2. One thread per (b, f), f<128.
// ---------------------------------------------------------------------------
__global__ void scan2(const float* __restrict__ y2, float* __restrict__ s2) {
    int idx = blockIdx.x * 256 + threadIdx.x;   // 16384 = 128 b * 128 f
    int b = idx >> 7, f = idx & 127;
    const float* p = y2 + (long)b * 100 * 128 + f;
    float* o = s2 + (long)b * 100 * 128 + f;
    float v1 = 0.f, v2 = 0.f;
    float xt = p[0];
    #pragma unroll 5
    for (int t = 0; t < 100; ++t) {
        float xn = (t < 99) ? p[(t + 1) * 128] : 0.f;
        v1 = ALPHA * v1 + xt;
        v2 = ALPHA * v2 + v1;
        float s = (v2 >= 1.f) ? 1.f : 0.f;
        o[t * 128] = s;
        v2 -= s;
        xt = xn;
    }
}

// ---------------------------------------------------------------------------
// K5: out[bt][o] = sum_f s2[bt][f] * lin_w[o][f].  One wave per bt.
// ---------------------------------------------------------------------------
__global__ __launch_bounds__(256) void linear_out(const float* __restrict__ s2,
                                                  const float* __restrict__ lw,
                                                  float* __restrict__ out) {
    int tid = threadIdx.x;
    long bt = (long)blockIdx.x * 4 + (tid >> 6);
    int lane = tid & 63;
    float2 v = *(const float2*)(s2 + bt * 128 + lane * 2);
    float w00 = lw[lane * 2], w01 = lw[lane * 2 + 1];
    float w10 = lw[128 + lane * 2], w11 = lw[128 + lane * 2 + 1];
    float a0 = v.x * w00 + v.y * w01;
    float a1 = v.x * w10 + v.y * w11;
    #pragma unroll
    for (int off = 32; off; off >>= 1) {
        a0 += __shfl_down(a0, off);
        a1 += __shfl_down(a1, off);
    }
    if (lane == 0) { out[bt * 2] = a0; out[bt * 2 + 1] = a1; }
}

extern "C" void kernel_launch(void* const* d_in, const int* in_sizes, int n_in,
                              void* d_out, int out_size, void* d_ws, size_t ws_size,
                              hipStream_t stream) {
    const float* x  = (const float*)d_in[0];   // [128,100,2,32,32]
    const float* w1 = (const float*)d_in[1];   // [4,2,5,5]
    const float* w2 = (const float*)d_in[2];   // [8,4,3,3]
    const float* lw = (const float*)d_in[3];   // [2,128]
    float* out = (float*)d_out;                // [128,100,2]

    float* ws   = (float*)d_ws;
    float* w1e  = ws;                 // 512 floats
    float* w2e  = ws + 512;           // 512 floats
    float* bufA = ws + 1024;          // 12800*256 = 3276800 floats (y1, later y2)
    float* bufB = bufA + 3276800;     // 3276800 floats (spk1, later s2)

    prep_weights<<<4, 256, 0, stream>>>(w1, w2, w1e, w2e);
    conv1_pool<<<3200, 256, 0, stream>>>(x, w1e, bufA);       // y1  -> bufA
    scan1<<<128, 256, 0, stream>>>(bufA, bufB);               // spk -> bufB
    conv2_pool<<<6400, 256, 0, stream>>>(bufB, w2e, bufA);    // y2  -> bufA
    scan2<<<64, 256, 0, stream>>>(bufA, bufB);                // s2  -> bufB
    linear_out<<<3200, 256, 0, stream>>>(bufB, lw, out);      // out
}